// Round 4
// baseline (238.249 us; speedup 1.0000x reference)
//
#include <hip/hip_runtime.h>

// APoT (8-bit, m=2) quantizer, eval forward — bit-logic + persistent
// grid-stride pipeline.
//
// Codebook = {0, ±2^-p, ±(2^-p + 2^-q)}: every level is an fp32 with at most
// TWO mantissa bits set, finest bit 2^-15 absolute. Nearest-level with
// searchsorted/argmin-first tie-break == exact integer logic on the bit
// pattern of |xn| (all reference fp32 subtractions are exact), verified
// absmax == 0.0 in R1/R2. IEEE RN divide retained: xn must bit-match numpy
// (reciprocal-multiply can flip halfway ties -> up to 0.625 error).
//
// Structure: 2048 persistent blocks (8/CU), grid-stride float4 loop with
// next-iteration load prefetch so each wave keeps loads in flight
// continuously instead of one-shot load/stall/store blocks (R2 was 3.8 TB/s;
// copy-style grid-stride kernels reach 6.3 TB/s on this chip).

typedef float vfloat4 __attribute__((ext_vector_type(4)));

__device__ __forceinline__ float apot_q(float xn) {
    const unsigned u = __float_as_uint(xn);
    const unsigned s = u & 0x80000000u;
    const unsigned a = u & 0x7FFFFFFFu;   // |xn| bits, <= 0x3F800000 (1.0f)
    unsigned q;
    if (a >= 0x38000000u) {               // |xn| >= 2^-15 : ~99.999% of data
        const unsigned e    = a >> 23;          // 112..127
        const unsigned m    = a & 0x7FFFFFu;
        const unsigned base = a - m;            // e<<23
        const unsigned g    = 1u << (135u - e); // finest grid bit (abs 2^-15)
        const unsigned L    = 31u - __clz(m | 1u);
        const unsigned bit  = 1u << L;
        const bool fine = (m < g);
        const unsigned lo  = fine ? base       : (base | bit);
        const unsigned hi  = fine ? (base + g) : (base + (bit << 1));
        const unsigned mid = fine ? g : (bit + (bit << 1));
        const unsigned m2  = m + m;
        const bool pickLo = (m2 < mid) | ((m2 == mid) & (s == 0u));
        q = pickLo ? lo : hi;
    } else {
        const unsigned T0 = 0x37800000u;  // 2^-16 midpoint of {0, 2^-15}
        const bool pickZero = (a < T0) | ((a == T0) & (s == 0u));
        q = pickZero ? 0u : 0x38000000u;
    }
    return __uint_as_float(q | s);
}

__device__ __forceinline__ vfloat4 quant4(vfloat4 v, float alpha_pos) {
    vfloat4 o;
    #pragma unroll
    for (int e = 0; e < 4; ++e) {
        // IEEE RN divide (no fast-math): bit-match numpy.
        float xn = fminf(1.0f, fmaxf(-1.0f, v[e] / alpha_pos));
        o[e] = apot_q(xn) * alpha_pos;
    }
    return o;
}

__global__ __launch_bounds__(256) void apot_quant_kernel(
    const float* __restrict__ x,
    const float* __restrict__ alpha,
    float* __restrict__ out,
    int n)
{
    const float alpha_pos = fabsf(alpha[0]) + 1e-5f;

    const int stride4 = (int)(gridDim.x * blockDim.x) * 4;  // elems/grid-iter
    int idx = (int)(blockIdx.x * blockDim.x + threadIdx.x) * 4;

    if (idx + 3 >= n) {
        // scalar stragglers if n % 4 != 0 (not hit for 4096x8192)
        for (int k = idx; k < n; ++k) {
            float xn = fminf(1.0f, fmaxf(-1.0f, x[k] / alpha_pos));
            out[k] = apot_q(xn) * alpha_pos;
        }
        return;
    }

    // number of full float4 tiles this thread owns (n % 4 == 0 assumed here)
    const int iters = (n - idx - 4) / stride4 + 1;

    // software pipeline: next load in flight while current tile computes/stores
    vfloat4 cur = *(const vfloat4*)(x + idx);
    #pragma unroll 2
    for (int k = 1; k < iters; ++k) {
        const vfloat4 nxt = *(const vfloat4*)(x + idx + stride4);
        const vfloat4 o = quant4(cur, alpha_pos);
        __builtin_nontemporal_store(o, (vfloat4*)(out + idx));
        cur = nxt;
        idx += stride4;
    }
    __builtin_nontemporal_store(quant4(cur, alpha_pos), (vfloat4*)(out + idx));
}

extern "C" void kernel_launch(void* const* d_in, const int* in_sizes, int n_in,
                              void* d_out, int out_size, void* d_ws, size_t ws_size,
                              hipStream_t stream) {
    const float* x     = (const float*)d_in[0];
    const float* alpha = (const float*)d_in[1];
    // d_in[2] (codebook) is implied by the bit logic; not read.
    float* out         = (float*)d_out;

    const int n = in_sizes[0];   // 33,554,432
    // Persistent: 8 blocks/CU x 256 CUs = 2048 blocks, full 2048-thread/CU
    // residency; each thread loops ~16 float4 tiles.
    const int block = 256;
    int grid = 2048;
    const int maxTiles = (n + block * 4 - 1) / (block * 4);
    if (grid > maxTiles) grid = maxTiles;   // tiny-n safety

    apot_quant_kernel<<<grid, block, 0, stream>>>(x, alpha, out, n);
}

// Round 5
// 221.971 us; speedup vs baseline: 1.0733x; 1.0733x over previous
//
#include <hip/hip_runtime.h>

// APoT (8-bit, m=2) quantizer, eval forward — bit-logic, divide-free fast path.
//
// Codebook = {0, ±2^-p, ±(2^-p + 2^-q)}: every level is an fp32 with at most
// TWO mantissa bits set, finest bit 2^-15 absolute. Nearest-level with
// searchsorted/argmin-first tie-break == exact integer logic on the bit
// pattern of |xn| (verified absmax == 0.0, R1-R3).
//
// R4: the per-element IEEE divide (v_div_scale/v_rcp/v_div_fmas/v_div_fixup,
// ~10-inst serial chain, 43% VALUBusy in R3) is replaced by q0 = x * (1/alpha)
// (1 mul; divisor is uniform). q0 is within <=3 mantissa-units of RN(x/alpha).
// The level decision uses signed distance d = 2m - mid to the bracketing
// midpoint: |d| > 8 guarantees the decision matches the exact quotient's
// (error bound 6 < 8; binade edges are codebook levels, decision-consistent
// from both sides). Rare lanes with |d| <= 8 (~1e-6, incl. all exact ties)
// redo the true IEEE divide under exec mask -> bit-exactness preserved.
//
// Tie semantics (argmin-first): xn>0 tie -> smaller value; xn<0 -> larger mag.

typedef float vfloat4 __attribute__((ext_vector_type(4)));

__device__ __forceinline__ unsigned apot_pick(unsigned a, unsigned s, int& d) {
    // a = bit pattern of clamped |xn| (<= 0x3F800000). Returns level bits
    // (sign excluded); d = signed distance of 2m from the decision midpoint.
    unsigned q;
    if (a >= 0x38000000u) {               // |xn| >= 2^-15 : ~99.999% of data
        const unsigned e    = a >> 23;          // 112..127
        const unsigned m    = a & 0x7FFFFFu;
        const unsigned base = a - m;            // e<<23
        const unsigned g    = 1u << (135u - e); // finest grid bit (abs 2^-15)
        const unsigned L    = 31u - __clz(m | 1u);
        const unsigned bit  = 1u << L;
        const bool fine = (m < g);
        const unsigned lo  = fine ? base       : (base | bit);
        const unsigned hi  = fine ? (base + g) : (base + (bit << 1));
        const unsigned mid = fine ? g : (bit + (bit << 1));
        d = (int)(m + m) - (int)mid;
        const bool pickLo = (d < 0) | ((d == 0) & (s == 0u));
        q = pickLo ? lo : hi;
    } else {
        // |xn| < 2^-15: neighbors {0, 2^-15}; midpoint 2^-16
        d = (int)a - (int)0x37800000u;
        const bool pickZero = (d < 0) | ((d == 0) & (s == 0u));
        q = pickZero ? 0u : 0x38000000u;
    }
    return q;
}

__device__ __forceinline__ float apot_q1(float xv, float r, float alpha_pos) {
    // fast path: approximate quotient, exact-decision margin test
    const float q0 = xv * r;
    float xn = fminf(1.0f, fmaxf(-1.0f, q0));
    unsigned u = __float_as_uint(xn);
    unsigned s = u & 0x80000000u;
    int d;
    unsigned q = apot_pick(u & 0x7FFFFFFFu, s, d);
    if (d < 9 && d > -9) {
        // within margin of a decision boundary: redo with exact IEEE divide
        const float xe = fminf(1.0f, fmaxf(-1.0f, xv / alpha_pos));
        const unsigned ue = __float_as_uint(xe);
        s = ue & 0x80000000u;
        q = apot_pick(ue & 0x7FFFFFFFu, s, d);
    }
    return __uint_as_float(q | s) * alpha_pos;
}

__device__ __forceinline__ vfloat4 quant4(vfloat4 v, float r, float alpha_pos) {
    vfloat4 o;
    #pragma unroll
    for (int e = 0; e < 4; ++e) o[e] = apot_q1(v[e], r, alpha_pos);
    return o;
}

// One-shot blocks (dispatcher churn pipelines memory better than the
// persistent loop did in R3: 71 vs 81.6 us). 16 elems/thread, all 4 dwordx4
// loads issued before any dependent ALU; non-temporal touch-once streams.
__global__ __launch_bounds__(256) void apot_quant_kernel(
    const float* __restrict__ x,
    const float* __restrict__ alpha,
    float* __restrict__ out,
    int n)
{
    const float alpha_pos = fabsf(alpha[0]) + 1e-5f;
    const float r = 1.0f / alpha_pos;   // uniform: one divide per thread

    const int blockStart = blockIdx.x * (256 * 16);
    const int i0 = blockStart + (int)threadIdx.x * 4;

    if (blockStart + 256 * 16 <= n) {
        vfloat4 v0 = __builtin_nontemporal_load((const vfloat4*)(x + i0));
        vfloat4 v1 = __builtin_nontemporal_load((const vfloat4*)(x + i0 + 1024));
        vfloat4 v2 = __builtin_nontemporal_load((const vfloat4*)(x + i0 + 2048));
        vfloat4 v3 = __builtin_nontemporal_load((const vfloat4*)(x + i0 + 3072));
        __builtin_nontemporal_store(quant4(v0, r, alpha_pos), (vfloat4*)(out + i0));
        __builtin_nontemporal_store(quant4(v1, r, alpha_pos), (vfloat4*)(out + i0 + 1024));
        __builtin_nontemporal_store(quant4(v2, r, alpha_pos), (vfloat4*)(out + i0 + 2048));
        __builtin_nontemporal_store(quant4(v3, r, alpha_pos), (vfloat4*)(out + i0 + 3072));
    } else {
        // generic tail (not hit for 4096x8192: n % 4096 == 0)
        for (int t = 0; t < 4; ++t) {
            for (int e = 0; e < 4; ++e) {
                const int idx = i0 + t * 1024 + e;
                if (idx < n) out[idx] = apot_q1(x[idx], r, alpha_pos);
            }
        }
    }
}

extern "C" void kernel_launch(void* const* d_in, const int* in_sizes, int n_in,
                              void* d_out, int out_size, void* d_ws, size_t ws_size,
                              hipStream_t stream) {
    const float* x     = (const float*)d_in[0];
    const float* alpha = (const float*)d_in[1];
    // d_in[2] (codebook) is implied by the bit logic; not read.
    float* out         = (float*)d_out;

    const int n = in_sizes[0];            // 33,554,432
    const int elemsPerBlock = 256 * 16;
    const int grid = (n + elemsPerBlock - 1) / elemsPerBlock;  // 8192

    apot_quant_kernel<<<grid, 256, 0, stream>>>(x, alpha, out, n);
}